// Round 11
// baseline (196.388 us; speedup 1.0000x reference)
//
#include <hip/hip_runtime.h>
#include <hip/hip_bf16.h>
#include <math.h>

#define EPS 1e-8f

// ---------- helpers ----------
__device__ __forceinline__ unsigned fenc(float f) {
    unsigned u = __float_as_uint(f);
    return (u & 0x80000000u) ? ~u : (u | 0x80000000u);
}
__device__ __forceinline__ float fdec(unsigned e) {
    unsigned u = (e & 0x80000000u) ? (e & 0x7FFFFFFFu) : ~e;
    return __uint_as_float(u);
}

__device__ __forceinline__ float block_sum(float v, float* red) {
    red[threadIdx.x] = v;
    __syncthreads();
    for (int k = 128; k > 0; k >>= 1) {
        if (threadIdx.x < k) red[threadIdx.x] += red[threadIdx.x + k];
        __syncthreads();
    }
    float r = red[0];
    __syncthreads();
    return r;
}

// ---------- kernels ----------
// per-group histogram: gh[g*1024 + c]
__global__ void k_ghist(const int* tgt, int* gh, int B) {
    __shared__ int lh[1024];
    int g = blockIdx.x, t = threadIdx.x;
    lh[t] = 0; lh[t + 256] = 0; lh[t + 512] = 0; lh[t + 768] = 0;
    __syncthreads();
    int i = g * 256 + t;
    if (i < B) atomicAdd(&lh[tgt[i]], 1);
    __syncthreads();
    int* dst = gh + g * 1024;
    dst[t] = lh[t]; dst[t + 256] = lh[t + 256];
    dst[t + 512] = lh[t + 512]; dst[t + 768] = lh[t + 768];
}

// in-place exclusive scan of gh over groups (per class), totals -> counts,
// class-exclusive-scan -> offsets. One block, 1024 threads. Also inits minmax.
__global__ void k_bases(int* gh, int* counts, int* offsets, unsigned* minmax, int G, int C) {
    __shared__ int buf[1024];
    int c = threadIdx.x;
    if (c == 0) { minmax[0] = 0xFFFFFFFFu; minmax[1] = 0u; }
    int run = 0;
#pragma unroll 16
    for (int g = 0; g < G; g++) {
        int v = gh[g * 1024 + c];
        gh[g * 1024 + c] = run;
        run += v;
    }
    if (c < C) counts[c] = run;
    int v0 = (c < C) ? run : 0;
    buf[c] = v0;
    __syncthreads();
    for (int off = 1; off < 1024; off <<= 1) {
        int v = (c >= off) ? buf[c - off] : 0;
        __syncthreads();
        buf[c] += v;
        __syncthreads();
    }
    if (c < C) offsets[c] = buf[c] - v0;
}

// stable rank within group via LDS compare-count; deterministic idx
__global__ void k_rank_scatter(const int* tgt, const int* offsets, const int* gh,
                               int* idx, int B) {
    __shared__ int lt[256];
    int g = blockIdx.x, t = threadIdx.x;
    int i = g * 256 + t;
    int my = (i < B) ? tgt[i] : -1;
    lt[t] = my;
    __syncthreads();
    if (i < B) {
        int rank = 0;
        for (int j = 0; j < t; j++) rank += (lt[j] == my);
        idx[offsets[my] + gh[g * 1024 + my] + rank] = i;
    }
}

// one block (256 thr) per class; D = 1024 (256 float4). Also emits norms.
__global__ void k_ftab(const float* feat, const float* finit, const int* counts,
                       const int* offsets, const int* idx, float* ftab, float* norms,
                       int C, int D) {
    __shared__ float red[256];
    int c = blockIdx.x, t = threadIdx.x;
    int n = counts[c];
    float o0, o1, o2, o3;
    if (n == 0) {
        float4 v = ((const float4*)(finit + (long)c * D))[t];
        o0 = v.x; o1 = v.y; o2 = v.z; o3 = v.w;
    } else {
        float4 acc = {0.f, 0.f, 0.f, 0.f};
        int o = offsets[c];
        for (int i = 0; i < n; i++) {
            float4 v = ((const float4*)(feat + (long)idx[o + i] * D))[t];
            acc.x += v.x; acc.y += v.y; acc.z += v.z; acc.w += v.w;
        }
        float inv = 1.0f / (float)n;
        o0 = acc.x * inv; o1 = acc.y * inv; o2 = acc.z * inv; o3 = acc.w * inv;
    }
    float* dst = ftab + (long)c * D + t * 4;   // ftab only 8B-aligned -> scalar writes
    dst[0] = o0; dst[1] = o1; dst[2] = o2; dst[3] = o3;
    float ss = o0 * o0 + o1 * o1 + o2 * o2 + o3 * o3;
    ss = block_sum(ss, red);
    if (t == 0) norms[c] = sqrtf(ss);
}

// one block per class; C2 = 1000 columns (250 float4 per row; logits rows 16B-aligned)
__global__ void k_ltab(const float* logits, const float* linit, const int* counts,
                       const int* offsets, const int* idx, float* ltab, int C, int C2) {
    int c = blockIdx.x, t = threadIdx.x;
    int n = counts[c];
    if (n == 0) {
        for (int d = t; d < C2; d += 256) ltab[(long)c * C2 + d] = linit[(long)c * C2 + d];
        return;
    }
    int nv = C2 >> 2;                 // 250
    if (t < nv) {
        float4 acc = {0.f, 0.f, 0.f, 0.f};
        int o = offsets[c];
        for (int i = 0; i < n; i++) {
            float4 v = ((const float4*)(logits + (long)idx[o + i] * C2))[t];
            acc.x += v.x; acc.y += v.y; acc.z += v.z; acc.w += v.w;
        }
        float inv = 1.0f / (float)n;
        float* dst = ltab + (long)c * C2 + t * 4;  // 8B-aligned -> scalar writes
        dst[0] = acc.x * inv;
        dst[1] = acc.y * inv;
        dst[2] = acc.z * inv;
        dst[3] = acc.w * inv;
    }
}

// Raw-dot triangular GEMM, NO atomics: one block per (upper-tri 64x64 tile, K-half).
// blockIdx.y = ks selects K range [ks*D2, ks*D2+D2) and output buffer (S0 or S1).
// 512 thr (8 waves), 8x8 per-thread blocking, intra-block split-K=8 (kz = t>>6),
// double-buffered LDS, sequential deterministic kz-reduction, cooperative
// coalesced stores of S(r,c) and mirror S(c,r). Each S-half element written once.
__global__ __launch_bounds__(512) void k_gemm_tri(const float* A, float* S0, float* S1,
                                                  int C, int D, int D2, int NT) {
    __shared__ __align__(16) float As[2][32][68];
    __shared__ __align__(16) float Bs[2][32][68];
    __shared__ float racc[64 * 69];   // kz-reduction + output staging, stride 69
    int t = threadIdx.x;
    int sp = t & 63;                  // spatial position 0..63
    int tx = sp & 7, ty = sp >> 3;    // 8x8 grid of 8x8-output threads
    int kz = t >> 6;                  // 0..7 (one wave per kz)
    int ks = blockIdx.y;              // K-half
    float* S = (ks == 0) ? S0 : S1;
    // decode triangular tile index
    int q = blockIdx.x, ti = 0;
    while (q >= NT - ti) { q -= NT - ti; ti++; }
    int tj = ti + q;
    int rb = ti * 64, cb = tj * 64;
    int sr = t >> 3;                  // 0..63 staging row
    int sl = t & 7;                   // 0..7  staging k-lane
    int ga = rb + sr, gb = cb + sr;
    bool okA = ga < C, okB = gb < C;
    const float* arow = A + (long)ga * D + (long)ks * D2;
    const float* brow = A + (long)gb * D + (long)ks * D2;

    float pa[4], pb[4];
#define LOADT(K0)                                                          \
    _Pragma("unroll") for (int j = 0; j < 4; j++) {                        \
        int k = (K0) + sl + 8 * j;                                         \
        pa[j] = okA ? arow[k] : 0.f;                                       \
        pb[j] = okB ? brow[k] : 0.f;                                       \
    }
#define STORET(BUF)                                                        \
    _Pragma("unroll") for (int j = 0; j < 4; j++) {                        \
        int k = sl + 8 * j;                                                \
        As[BUF][k][sr] = pa[j];                                            \
        Bs[BUF][k][sr] = pb[j];                                            \
    }

    LOADT(0)
    STORET(0)
    __syncthreads();
    float acc[8][8] = {};
    int kbase = kz * 4;
    int nsteps = D2 >> 5;
    for (int step = 0; step < nsteps; step++) {
        int cur = step & 1;
        if (step < nsteps - 1) {
            LOADT((step + 1) * 32)
        }
#pragma unroll
        for (int kk = 0; kk < 4; kk += 2) {
            float4 a0[2], a1[2], b0[2], b1[2];
#pragma unroll
            for (int u = 0; u < 2; u++) {
                int k = kbase + kk + u;
                a0[u] = *reinterpret_cast<const float4*>(&As[cur][k][ty * 8]);
                a1[u] = *reinterpret_cast<const float4*>(&As[cur][k][ty * 8 + 4]);
                b0[u] = *reinterpret_cast<const float4*>(&Bs[cur][k][tx * 8]);
                b1[u] = *reinterpret_cast<const float4*>(&Bs[cur][k][tx * 8 + 4]);
            }
#pragma unroll
            for (int u = 0; u < 2; u++) {
                float a[8] = {a0[u].x, a0[u].y, a0[u].z, a0[u].w,
                              a1[u].x, a1[u].y, a1[u].z, a1[u].w};
                float b[8] = {b0[u].x, b0[u].y, b0[u].z, b0[u].w,
                              b1[u].x, b1[u].y, b1[u].z, b1[u].w};
#pragma unroll
                for (int i = 0; i < 8; i++)
#pragma unroll
                    for (int j = 0; j < 8; j++) acc[i][j] += a[i] * b[j];
            }
        }
        if (step < nsteps - 1) {
            STORET(cur ^ 1)
        }
        __syncthreads();
    }
#undef LOADT
#undef STORET

    // sequential deterministic reduction into kz=0: acc0 += acc1; += ... += acc7
#pragma unroll
    for (int src = 1; src < 8; src++) {
        if (kz == src) {
#pragma unroll
            for (int i = 0; i < 8; i++)
#pragma unroll
                for (int j = 0; j < 8; j++) racc[sp * 69 + i * 8 + j] = acc[i][j];
        }
        __syncthreads();
        if (kz == 0) {
#pragma unroll
            for (int i = 0; i < 8; i++)
#pragma unroll
                for (int j = 0; j < 8; j++) acc[i][j] += racc[sp * 69 + i * 8 + j];
        }
        __syncthreads();
    }

    // stage final 64x64 tile into racc as OutT[row][col] (stride 69)
    if (kz == 0) {
#pragma unroll
        for (int i = 0; i < 8; i++)
#pragma unroll
            for (int j = 0; j < 8; j++)
                racc[(ty * 8 + i) * 69 + tx * 8 + j] = acc[i][j];
    }
    __syncthreads();

    // cooperative coalesced stores: all 512 threads
    int r0 = t >> 3;                  // 0..63
    int cbl = (t & 7) * 8;            // local col base
    int gr = rb + r0;
    bool edge = (tj == NT - 1);
    if (gr < C) {
        float v[8];
#pragma unroll
        for (int m = 0; m < 8; m++) v[m] = racc[r0 * 69 + cbl + m];
        float* dst = S + (long)gr * C + cb + cbl;
        if (!edge) {
#pragma unroll
            for (int m = 0; m < 4; m++)
                *reinterpret_cast<float2*>(dst + 2 * m) = make_float2(v[2 * m], v[2 * m + 1]);
        } else {
#pragma unroll
            for (int m = 0; m < 8; m++)
                if (cb + cbl + m < C) dst[m] = v[m];
        }
    }
    if (ti != tj) {
        int cc0 = cb + r0;
        if (cc0 < C) {
            float w[8];
#pragma unroll
            for (int m = 0; m < 8; m++) w[m] = racc[(cbl + m) * 69 + r0];
            // mirror rows rb+cbl+m: ti<tj implies ti<=NT-2 -> always < C
            float* dst = S + (long)cc0 * C + rb + cbl;
#pragma unroll
            for (int m = 0; m < 4; m++)
                *reinterpret_cast<float2*>(dst + 2 * m) = make_float2(w[2 * m], w[2 * m + 1]);
        }
    }
}

// per-row: best/argmax (excl diag) of cos values + global min/max (incl diag).
// S = Sa (+ Sb if two): raw dots; divide by norms on the fly (min-max scaling is
// monotone, so argmax/max on raw cos == on scaled; scaling applied in k_floss).
__global__ void k_rowmax(const float* Sa, const float* Sb, int two, const float* norms,
                         unsigned* minmax, float* simraw, int* simcls, int C) {
    __shared__ float invn[1024];
    __shared__ float rv[256], rmn[256], rmx[256];
    __shared__ int ri[256];
    int c = blockIdx.x, t = threadIdx.x;
    for (int j = t; j < C; j += 256) invn[j] = 1.f / norms[j];
    __syncthreads();
    float inc = invn[c];
    float best = -INFINITY, lmin = INFINITY, lmax = -INFINITY;
    int bi = 0x7FFFFFFF;
    for (int j = t; j < C; j += 256) {
        float v = Sa[(long)c * C + j];
        if (two) v += Sb[(long)c * C + j];
        v *= inc * invn[j];
        lmin = fminf(lmin, v);
        lmax = fmaxf(lmax, v);
        if (j != c && v > best) { best = v; bi = j; }
    }
    rv[t] = best; ri[t] = bi; rmn[t] = lmin; rmx[t] = lmax;
    __syncthreads();
    for (int k = 128; k > 0; k >>= 1) {
        if (t < k) {
            if (rv[t + k] > rv[t] || (rv[t + k] == rv[t] && ri[t + k] < ri[t])) {
                rv[t] = rv[t + k];
                ri[t] = ri[t + k];
            }
            rmn[t] = fminf(rmn[t], rmn[t + k]);
            rmx[t] = fmaxf(rmx[t], rmx[t + k]);
        }
        __syncthreads();
    }
    if (t == 0) {
        simraw[c] = rv[0];
        simcls[c] = ri[0];
        atomicMin(&minmax[0], fenc(rmn[0]));
        atomicMax(&minmax[1], fenc(rmx[0]));
    }
}

// one wave per sample; 4 samples per block; vectorized loads.
// simval scaling (x - cmin)/(cmax - cmin) applied here.
__global__ void k_floss(const float* feat, const float* ftab, const float* norms, const int* tgt,
                        const unsigned* minmax, const float* simraw, const int* simcls,
                        float* fpart, int B, int D) {
    int wid = threadIdx.x >> 6, lane = threadIdx.x & 63;
    int s = blockIdx.x * 4 + wid;
    int cls = tgt[s];
    int sc = simcls[cls];
    const float4* f4 = (const float4*)(feat + (long)s * D);           // 16B-aligned
    const float2* ft2 = (const float2*)(ftab + (long)cls * D);        // 8B-aligned
    const float2* fs2 = (const float2*)(ftab + (long)sc * D);
    float d1 = 0.f, d2 = 0.f, nf2 = 0.f;
#pragma unroll
    for (int i = 0; i < 4; i++) {
        int j = lane + i * 64;           // float4 index, 0..255
        float4 x = f4[j];
        float2 a0 = ft2[2 * j], a1 = ft2[2 * j + 1];
        float2 b0 = fs2[2 * j], b1 = fs2[2 * j + 1];
        d1 += x.x * a0.x + x.y * a0.y + x.z * a1.x + x.w * a1.y;
        d2 += x.x * b0.x + x.y * b0.y + x.z * b1.x + x.w * b1.y;
        nf2 += x.x * x.x + x.y * x.y + x.z * x.z + x.w * x.w;
    }
    for (int o = 32; o > 0; o >>= 1) {
        d1 += __shfl_down(d1, o);
        d2 += __shfl_down(d2, o);
        nf2 += __shfl_down(nf2, o);
    }
    __shared__ float part[4];
    if (lane == 0) {
        float cmin = fdec(minmax[0]);
        float cmax = fdec(minmax[1]);
        float sv = (simraw[cls] - cmin) / (cmax - cmin);
        float nf = fmaxf(sqrtf(nf2), EPS);
        float nt = fmaxf(norms[cls], EPS);
        float ns = fmaxf(norms[sc], EPS);
        part[wid] = (1.f - d1 / (nf * nt)) + (d2 / (nf * ns)) * sv;
    }
    __syncthreads();
    if (threadIdx.x == 0) fpart[blockIdx.x] = part[0] + part[1] + part[2] + part[3];
}

// one WAVE per sample; 4 samples per block; float2 loads, shuffle reductions. C even.
__global__ __launch_bounds__(256) void k_kl(const float* logits, const float* LT, const int* tgt,
                                            float* klpart, int B, int C) {
    int wid = threadIdx.x >> 6, lane = threadIdx.x & 63;
    int s = blockIdx.x * 4 + wid;
    int cls = tgt[s];
    const float2* a2 = (const float2*)(LT + (long)cls * C);      // 8B-aligned
    const float2* b2 = (const float2*)(logits + (long)s * C);    // 16B-aligned
    int H = C >> 1;   // 500
    float ta[16], tb[16];
    float m1 = -INFINITY, m2 = -INFINITY;
#pragma unroll
    for (int p = 0; p < 8; p++) {
        int j = lane + (p << 6);
        if (j < H) {
            float2 va = a2[j], vb = b2[j];
            ta[2 * p] = va.x; ta[2 * p + 1] = va.y;
            tb[2 * p] = vb.x; tb[2 * p + 1] = vb.y;
            m1 = fmaxf(m1, fmaxf(va.x, va.y));
            m2 = fmaxf(m2, fmaxf(vb.x, vb.y));
        } else {
            ta[2 * p] = -INFINITY; ta[2 * p + 1] = -INFINITY;
            tb[2 * p] = -INFINITY; tb[2 * p + 1] = -INFINITY;
        }
    }
#pragma unroll
    for (int o = 32; o > 0; o >>= 1) {
        m1 = fmaxf(m1, __shfl_xor(m1, o));
        m2 = fmaxf(m2, __shfl_xor(m2, o));
    }
    float e1[16];
    float s1 = 0.f, s2 = 0.f;
#pragma unroll
    for (int i = 0; i < 16; i++) {
        int j = lane + ((i >> 1) << 6);
        if (j < H) {
            e1[i] = expf(ta[i] - m1);
            s1 += e1[i];
            s2 += expf(tb[i] - m2);
        } else {
            e1[i] = 0.f;
        }
    }
#pragma unroll
    for (int o = 32; o > 0; o >>= 1) {
        s1 += __shfl_xor(s1, o);
        s2 += __shfl_xor(s2, o);
    }
    float ls1 = logf(s1), ls2 = logf(s2);
    float inv = 1.f / s1;
    float kl = 0.f;
#pragma unroll
    for (int i = 0; i < 16; i++) {
        int j = lane + ((i >> 1) << 6);
        if (j < H) {
            float lp = ta[i] - m1 - ls1;
            float lq = tb[i] - m2 - ls2;
            kl += e1[i] * inv * (lp - lq);
        }
    }
#pragma unroll
    for (int o = 32; o > 0; o >>= 1) kl += __shfl_xor(kl, o);
    if (lane == 0) klpart[s] = kl;
}

__global__ void k_final(const float* fpart, const float* klpart, float* out, int nf, int nk) {
    __shared__ float red[256];
    float a = 0.f;
    for (int i = threadIdx.x; i < nf; i += 256) a += fpart[i];
    a = block_sum(a, red);
    float b = 0.f;
    for (int i = threadIdx.x; i < nk; i += 256) b += klpart[i];
    b = block_sum(b, red);
    if (threadIdx.x == 0) {
        out[0] = a;
        out[1] = b;
    }
}

extern "C" void kernel_launch(void* const* d_in, const int* in_sizes, int n_in,
                              void* d_out, int out_size, void* d_ws, size_t ws_size,
                              hipStream_t stream) {
    const float* feature = (const float*)d_in[0];
    const float* logits  = (const float*)d_in[1];
    const int*   targets = (const int*)d_in[2];
    const float* finit   = (const float*)d_in[3];
    const float* linit   = (const float*)d_in[4];

    const int B = in_sizes[2];                 // 16384
    const int D = in_sizes[0] / B;             // 1024
    const int C = in_sizes[3] / D;             // 1000

    float* out = (float*)d_out;
    float* ftab = out + 2;                     // [C, D]
    float* ltab = out + 2 + (long)C * D;       // [C, C]  (S0 scratch + ghist scratch)

    const int G = (B + 255) / 256;             // 64 groups
    const int NT = (C + 63) / 64;              // 16 tiles per dim
    const int NTRI = NT * (NT + 1) / 2;        // 136 triangular tiles

    char* ws = (char*)d_ws;
    int*      counts  = (int*)(ws + 0);        // 1024
    int*      offsets = (int*)(ws + 4096);     // 1024
    int*      idx     = (int*)(ws + 12288);    // 16384
    float*    norms   = (float*)(ws + 77824);  // 1024
    float*    simraw  = (float*)(ws + 81920);  // 1024
    int*      simcls  = (int*)(ws + 86016);    // 1024
    unsigned* minmax  = (unsigned*)(ws + 90112); // 2
    float*    fpart   = (float*)(ws + 90368);  // 4096
    float*    klpart  = (float*)(ws + 106752); // 16384
    float*    S1      = (float*)(ws + 262144); // C*C floats (split-K partial), if room

    // split-K across blocks iff ws has room for the second partial buffer
    size_t need = 262144 + (size_t)C * C * sizeof(float);
    int split = (ws_size >= need) ? 1 : 0;

    // gh scratch lives in the (not-yet-written) ltab output region: G*1024 ints = 256 KB
    int* gh = (int*)ltab;

    k_ghist<<<G, 256, 0, stream>>>(targets, gh, B);
    k_bases<<<1, 1024, 0, stream>>>(gh, counts, offsets, minmax, G, C);
    k_rank_scatter<<<G, 256, 0, stream>>>(targets, offsets, gh, idx, B);

    k_ftab<<<C, 256, 0, stream>>>(feature, finit, counts, offsets, idx, ftab, norms, C, D);

    dim3 ggrid(NTRI, split ? 2 : 1);
    k_gemm_tri<<<ggrid, 512, 0, stream>>>(ftab, ltab /*S0*/, S1, C, D, split ? D / 2 : D, NT);
    k_rowmax<<<C, 256, 0, stream>>>(ltab /*S0*/, S1, split, norms, minmax, simraw, simcls, C);

    // now overwrite the S0 scratch with the real logit_table
    k_ltab<<<C, 256, 0, stream>>>(logits, linit, counts, offsets, idx, ltab, C, C);

    k_floss<<<B / 4, 256, 0, stream>>>(feature, ftab, norms, targets, minmax, simraw, simcls,
                                       fpart, B, D);
    k_kl<<<B / 4, 256, 0, stream>>>(logits, ltab, targets, klpart, B, C);
    k_final<<<1, 256, 0, stream>>>(fpart, klpart, out, B / 4, B);
}

// Round 12
// 191.454 us; speedup vs baseline: 1.0258x; 1.0258x over previous
//
#include <hip/hip_runtime.h>
#include <hip/hip_bf16.h>
#include <math.h>

#define EPS 1e-8f

// ---------- helpers ----------
__device__ __forceinline__ unsigned fenc(float f) {
    unsigned u = __float_as_uint(f);
    return (u & 0x80000000u) ? ~u : (u | 0x80000000u);
}
__device__ __forceinline__ float fdec(unsigned e) {
    unsigned u = (e & 0x80000000u) ? (e & 0x7FFFFFFFu) : ~e;
    return __uint_as_float(u);
}

__device__ __forceinline__ float block_sum(float v, float* red) {
    red[threadIdx.x] = v;
    __syncthreads();
    for (int k = 128; k > 0; k >>= 1) {
        if (threadIdx.x < k) red[threadIdx.x] += red[threadIdx.x + k];
        __syncthreads();
    }
    float r = red[0];
    __syncthreads();
    return r;
}

// ---------- kernels ----------
// per-group histogram: gh[g*1024 + c]
__global__ void k_ghist(const int* tgt, int* gh, int B) {
    __shared__ int lh[1024];
    int g = blockIdx.x, t = threadIdx.x;
    lh[t] = 0; lh[t + 256] = 0; lh[t + 512] = 0; lh[t + 768] = 0;
    __syncthreads();
    int i = g * 256 + t;
    if (i < B) atomicAdd(&lh[tgt[i]], 1);
    __syncthreads();
    int* dst = gh + g * 1024;
    dst[t] = lh[t]; dst[t + 256] = lh[t + 256];
    dst[t + 512] = lh[t + 512]; dst[t + 768] = lh[t + 768];
}

// in-place exclusive scan of gh over groups (per class), totals -> counts,
// class-exclusive-scan -> offsets. One block, 1024 threads. Also inits minmax.
__global__ void k_bases(int* gh, int* counts, int* offsets, unsigned* minmax, int G, int C) {
    __shared__ int buf[1024];
    int c = threadIdx.x;
    if (c == 0) { minmax[0] = 0xFFFFFFFFu; minmax[1] = 0u; }
    int run = 0;
#pragma unroll 16
    for (int g = 0; g < G; g++) {
        int v = gh[g * 1024 + c];
        gh[g * 1024 + c] = run;
        run += v;
    }
    if (c < C) counts[c] = run;
    int v0 = (c < C) ? run : 0;
    buf[c] = v0;
    __syncthreads();
    for (int off = 1; off < 1024; off <<= 1) {
        int v = (c >= off) ? buf[c - off] : 0;
        __syncthreads();
        buf[c] += v;
        __syncthreads();
    }
    if (c < C) offsets[c] = buf[c] - v0;
}

// stable rank within group via LDS compare-count; deterministic idx
__global__ void k_rank_scatter(const int* tgt, const int* offsets, const int* gh,
                               int* idx, int B) {
    __shared__ int lt[256];
    int g = blockIdx.x, t = threadIdx.x;
    int i = g * 256 + t;
    int my = (i < B) ? tgt[i] : -1;
    lt[t] = my;
    __syncthreads();
    if (i < B) {
        int rank = 0;
        for (int j = 0; j < t; j++) rank += (lt[j] == my);
        idx[offsets[my] + gh[g * 1024 + my] + rank] = i;
    }
}

// one block (256 thr) per class; D = 1024 (256 float4). Also emits norms.
// Software-pipelined gather (prefetch next idx + next row; order preserved).
__global__ void k_ftab(const float* feat, const float* finit, const int* counts,
                       const int* offsets, const int* idx, float* ftab, float* norms,
                       int C, int D) {
    __shared__ float red[256];
    int c = blockIdx.x, t = threadIdx.x;
    int n = counts[c];
    float o0, o1, o2, o3;
    if (n == 0) {
        float4 v = ((const float4*)(finit + (long)c * D))[t];
        o0 = v.x; o1 = v.y; o2 = v.z; o3 = v.w;
    } else {
        float4 acc = {0.f, 0.f, 0.f, 0.f};
        int o = offsets[c];
        int inx = idx[o];
        float4 nxt = ((const float4*)(feat + (long)inx * D))[t];
        for (int i = 0; i < n; i++) {
            float4 cur = nxt;
            if (i + 1 < n) {
                int in2 = idx[o + i + 1];
                nxt = ((const float4*)(feat + (long)in2 * D))[t];
            }
            acc.x += cur.x; acc.y += cur.y; acc.z += cur.z; acc.w += cur.w;
        }
        float inv = 1.0f / (float)n;
        o0 = acc.x * inv; o1 = acc.y * inv; o2 = acc.z * inv; o3 = acc.w * inv;
    }
    float* dst = ftab + (long)c * D + t * 4;   // ftab only 8B-aligned -> scalar writes
    dst[0] = o0; dst[1] = o1; dst[2] = o2; dst[3] = o3;
    float ss = o0 * o0 + o1 * o1 + o2 * o2 + o3 * o3;
    ss = block_sum(ss, red);
    if (t == 0) norms[c] = sqrtf(ss);
}

// one block per class; C2 = 1000 columns (250 float4 per row; logits rows 16B-aligned)
__global__ void k_ltab(const float* logits, const float* linit, const int* counts,
                       const int* offsets, const int* idx, float* ltab, int C, int C2) {
    int c = blockIdx.x, t = threadIdx.x;
    int n = counts[c];
    if (n == 0) {
        for (int d = t; d < C2; d += 256) ltab[(long)c * C2 + d] = linit[(long)c * C2 + d];
        return;
    }
    int nv = C2 >> 2;                 // 250
    if (t < nv) {
        float4 acc = {0.f, 0.f, 0.f, 0.f};
        int o = offsets[c];
        int inx = idx[o];
        float4 nxt = ((const float4*)(logits + (long)inx * C2))[t];
        for (int i = 0; i < n; i++) {
            float4 cur = nxt;
            if (i + 1 < n) {
                int in2 = idx[o + i + 1];
                nxt = ((const float4*)(logits + (long)in2 * C2))[t];
            }
            acc.x += cur.x; acc.y += cur.y; acc.z += cur.z; acc.w += cur.w;
        }
        float inv = 1.0f / (float)n;
        float* dst = ltab + (long)c * C2 + t * 4;  // 8B-aligned -> scalar writes
        dst[0] = acc.x * inv;
        dst[1] = acc.y * inv;
        dst[2] = acc.z * inv;
        dst[3] = acc.w * inv;
    }
}

// Raw-dot triangular GEMM, NO atomics: one block per (upper-tri 64x64 tile, K-slice).
// blockIdx.y = ks selects K range [ks*D2, (ks+1)*D2) and output buffer S[ks].
// 512 thr (8 waves), 8x8 per-thread blocking, intra-block split-K=8 (kz = t>>6),
// double-buffered LDS, sequential deterministic kz-reduction, cooperative
// coalesced stores of partial(r,c) and mirror partial(c,r). Each element of each
// buffer written exactly once -> deterministic.
__global__ __launch_bounds__(512) void k_gemm_tri(const float* A, float* S0, float* S1,
                                                  float* S2, float* S3,
                                                  int C, int D, int D2, int NT) {
    __shared__ __align__(16) float As[2][32][68];
    __shared__ __align__(16) float Bs[2][32][68];
    __shared__ float racc[64 * 69];   // kz-reduction + output staging, stride 69
    int t = threadIdx.x;
    int sp = t & 63;                  // spatial position 0..63
    int tx = sp & 7, ty = sp >> 3;    // 8x8 grid of 8x8-output threads
    int kz = t >> 6;                  // 0..7 (one wave per kz)
    int ks = blockIdx.y;              // K-slice
    float* S = (ks == 0) ? S0 : (ks == 1) ? S1 : (ks == 2) ? S2 : S3;
    // decode triangular tile index
    int q = blockIdx.x, ti = 0;
    while (q >= NT - ti) { q -= NT - ti; ti++; }
    int tj = ti + q;
    int rb = ti * 64, cb = tj * 64;
    int sr = t >> 3;                  // 0..63 staging row
    int sl = t & 7;                   // 0..7  staging k-lane
    int ga = rb + sr, gb = cb + sr;
    bool okA = ga < C, okB = gb < C;
    const float* arow = A + (long)ga * D + (long)ks * D2;
    const float* brow = A + (long)gb * D + (long)ks * D2;

    float pa[4], pb[4];
#define LOADT(K0)                                                          \
    _Pragma("unroll") for (int j = 0; j < 4; j++) {                        \
        int k = (K0) + sl + 8 * j;                                         \
        pa[j] = okA ? arow[k] : 0.f;                                       \
        pb[j] = okB ? brow[k] : 0.f;                                       \
    }
#define STORET(BUF)                                                        \
    _Pragma("unroll") for (int j = 0; j < 4; j++) {                        \
        int k = sl + 8 * j;                                                \
        As[BUF][k][sr] = pa[j];                                            \
        Bs[BUF][k][sr] = pb[j];                                            \
    }

    LOADT(0)
    STORET(0)
    __syncthreads();
    float acc[8][8] = {};
    int kbase = kz * 4;
    int nsteps = D2 >> 5;
    for (int step = 0; step < nsteps; step++) {
        int cur = step & 1;
        if (step < nsteps - 1) {
            LOADT((step + 1) * 32)
        }
#pragma unroll
        for (int kk = 0; kk < 4; kk += 2) {
            float4 a0[2], a1[2], b0[2], b1[2];
#pragma unroll
            for (int u = 0; u < 2; u++) {
                int k = kbase + kk + u;
                a0[u] = *reinterpret_cast<const float4*>(&As[cur][k][ty * 8]);
                a1[u] = *reinterpret_cast<const float4*>(&As[cur][k][ty * 8 + 4]);
                b0[u] = *reinterpret_cast<const float4*>(&Bs[cur][k][tx * 8]);
                b1[u] = *reinterpret_cast<const float4*>(&Bs[cur][k][tx * 8 + 4]);
            }
#pragma unroll
            for (int u = 0; u < 2; u++) {
                float a[8] = {a0[u].x, a0[u].y, a0[u].z, a0[u].w,
                              a1[u].x, a1[u].y, a1[u].z, a1[u].w};
                float b[8] = {b0[u].x, b0[u].y, b0[u].z, b0[u].w,
                              b1[u].x, b1[u].y, b1[u].z, b1[u].w};
#pragma unroll
                for (int i = 0; i < 8; i++)
#pragma unroll
                    for (int j = 0; j < 8; j++) acc[i][j] += a[i] * b[j];
            }
        }
        if (step < nsteps - 1) {
            STORET(cur ^ 1)
        }
        __syncthreads();
    }
#undef LOADT
#undef STORET

    // sequential deterministic reduction into kz=0: acc0 += acc1; += ... += acc7
#pragma unroll
    for (int src = 1; src < 8; src++) {
        if (kz == src) {
#pragma unroll
            for (int i = 0; i < 8; i++)
#pragma unroll
                for (int j = 0; j < 8; j++) racc[sp * 69 + i * 8 + j] = acc[i][j];
        }
        __syncthreads();
        if (kz == 0) {
#pragma unroll
            for (int i = 0; i < 8; i++)
#pragma unroll
                for (int j = 0; j < 8; j++) acc[i][j] += racc[sp * 69 + i * 8 + j];
        }
        __syncthreads();
    }

    // stage final 64x64 tile into racc as OutT[row][col] (stride 69)
    if (kz == 0) {
#pragma unroll
        for (int i = 0; i < 8; i++)
#pragma unroll
            for (int j = 0; j < 8; j++)
                racc[(ty * 8 + i) * 69 + tx * 8 + j] = acc[i][j];
    }
    __syncthreads();

    // cooperative coalesced stores: all 512 threads
    int r0 = t >> 3;                  // 0..63
    int cbl = (t & 7) * 8;            // local col base
    int gr = rb + r0;
    bool edge = (tj == NT - 1);
    if (gr < C) {
        float v[8];
#pragma unroll
        for (int m = 0; m < 8; m++) v[m] = racc[r0 * 69 + cbl + m];
        float* dst = S + (long)gr * C + cb + cbl;
        if (!edge) {
#pragma unroll
            for (int m = 0; m < 4; m++)
                *reinterpret_cast<float2*>(dst + 2 * m) = make_float2(v[2 * m], v[2 * m + 1]);
        } else {
#pragma unroll
            for (int m = 0; m < 8; m++)
                if (cb + cbl + m < C) dst[m] = v[m];
        }
    }
    if (ti != tj) {
        int cc0 = cb + r0;
        if (cc0 < C) {
            float w[8];
#pragma unroll
            for (int m = 0; m < 8; m++) w[m] = racc[(cbl + m) * 69 + r0];
            // mirror rows rb+cbl+m: ti<tj implies ti<=NT-2 -> always < C
            float* dst = S + (long)cc0 * C + rb + cbl;
#pragma unroll
            for (int m = 0; m < 4; m++)
                *reinterpret_cast<float2*>(dst + 2 * m) = make_float2(w[2 * m], w[2 * m + 1]);
        }
    }
}

// per-row: best/argmax (excl diag) of cos values + global min/max (incl diag).
// S = sum of nsplit partial buffers (fixed order -> deterministic); raw dots,
// divided by norms on the fly (min-max scaling is monotone, so argmax/max on raw
// cos == on scaled; scaling applied in k_floss).
__global__ void k_rowmax(const float* S0, const float* S1, const float* S2, const float* S3,
                         int nsplit, const float* norms, unsigned* minmax,
                         float* simraw, int* simcls, int C) {
    __shared__ float invn[1024];
    __shared__ float rv[256], rmn[256], rmx[256];
    __shared__ int ri[256];
    int c = blockIdx.x, t = threadIdx.x;
    for (int j = t; j < C; j += 256) invn[j] = 1.f / norms[j];
    __syncthreads();
    float inc = invn[c];
    float best = -INFINITY, lmin = INFINITY, lmax = -INFINITY;
    int bi = 0x7FFFFFFF;
    long rowo = (long)c * C;
    for (int j = t; j < C; j += 256) {
        float v = S0[rowo + j];
        if (nsplit > 1) v += S1[rowo + j];
        if (nsplit > 2) { v += S2[rowo + j]; v += S3[rowo + j]; }
        v *= inc * invn[j];
        lmin = fminf(lmin, v);
        lmax = fmaxf(lmax, v);
        if (j != c && v > best) { best = v; bi = j; }
    }
    rv[t] = best; ri[t] = bi; rmn[t] = lmin; rmx[t] = lmax;
    __syncthreads();
    for (int k = 128; k > 0; k >>= 1) {
        if (t < k) {
            if (rv[t + k] > rv[t] || (rv[t + k] == rv[t] && ri[t + k] < ri[t])) {
                rv[t] = rv[t + k];
                ri[t] = ri[t + k];
            }
            rmn[t] = fminf(rmn[t], rmn[t + k]);
            rmx[t] = fmaxf(rmx[t], rmx[t + k]);
        }
        __syncthreads();
    }
    if (t == 0) {
        simraw[c] = rv[0];
        simcls[c] = ri[0];
        atomicMin(&minmax[0], fenc(rmn[0]));
        atomicMax(&minmax[1], fenc(rmx[0]));
    }
}

// one wave per sample; 4 samples per block; vectorized loads.
// simval scaling (x - cmin)/(cmax - cmin) applied here.
__global__ void k_floss(const float* feat, const float* ftab, const float* norms, const int* tgt,
                        const unsigned* minmax, const float* simraw, const int* simcls,
                        float* fpart, int B, int D) {
    int wid = threadIdx.x >> 6, lane = threadIdx.x & 63;
    int s = blockIdx.x * 4 + wid;
    int cls = tgt[s];
    int sc = simcls[cls];
    const float4* f4 = (const float4*)(feat + (long)s * D);           // 16B-aligned
    const float2* ft2 = (const float2*)(ftab + (long)cls * D);        // 8B-aligned
    const float2* fs2 = (const float2*)(ftab + (long)sc * D);
    float d1 = 0.f, d2 = 0.f, nf2 = 0.f;
#pragma unroll
    for (int i = 0; i < 4; i++) {
        int j = lane + i * 64;           // float4 index, 0..255
        float4 x = f4[j];
        float2 a0 = ft2[2 * j], a1 = ft2[2 * j + 1];
        float2 b0 = fs2[2 * j], b1 = fs2[2 * j + 1];
        d1 += x.x * a0.x + x.y * a0.y + x.z * a1.x + x.w * a1.y;
        d2 += x.x * b0.x + x.y * b0.y + x.z * b1.x + x.w * b1.y;
        nf2 += x.x * x.x + x.y * x.y + x.z * x.z + x.w * x.w;
    }
    for (int o = 32; o > 0; o >>= 1) {
        d1 += __shfl_down(d1, o);
        d2 += __shfl_down(d2, o);
        nf2 += __shfl_down(nf2, o);
    }
    __shared__ float part[4];
    if (lane == 0) {
        float cmin = fdec(minmax[0]);
        float cmax = fdec(minmax[1]);
        float sv = (simraw[cls] - cmin) / (cmax - cmin);
        float nf = fmaxf(sqrtf(nf2), EPS);
        float nt = fmaxf(norms[cls], EPS);
        float ns = fmaxf(norms[sc], EPS);
        part[wid] = (1.f - d1 / (nf * nt)) + (d2 / (nf * ns)) * sv;
    }
    __syncthreads();
    if (threadIdx.x == 0) fpart[blockIdx.x] = part[0] + part[1] + part[2] + part[3];
}

// one WAVE per sample; 4 samples per block; float2 loads, shuffle reductions. C even.
// __expf/__logf: hardware transcendentals (tolerance is generous).
__global__ __launch_bounds__(256) void k_kl(const float* logits, const float* LT, const int* tgt,
                                            float* klpart, int B, int C) {
    int wid = threadIdx.x >> 6, lane = threadIdx.x & 63;
    int s = blockIdx.x * 4 + wid;
    int cls = tgt[s];
    const float2* a2 = (const float2*)(LT + (long)cls * C);      // 8B-aligned
    const float2* b2 = (const float2*)(logits + (long)s * C);    // 16B-aligned
    int H = C >> 1;   // 500
    float ta[16], tb[16];
    float m1 = -INFINITY, m2 = -INFINITY;
#pragma unroll
    for (int p = 0; p < 8; p++) {
        int j = lane + (p << 6);
        if (j < H) {
            float2 va = a2[j], vb = b2[j];
            ta[2 * p] = va.x; ta[2 * p + 1] = va.y;
            tb[2 * p] = vb.x; tb[2 * p + 1] = vb.y;
            m1 = fmaxf(m1, fmaxf(va.x, va.y));
            m2 = fmaxf(m2, fmaxf(vb.x, vb.y));
        } else {
            ta[2 * p] = -INFINITY; ta[2 * p + 1] = -INFINITY;
            tb[2 * p] = -INFINITY; tb[2 * p + 1] = -INFINITY;
        }
    }
#pragma unroll
    for (int o = 32; o > 0; o >>= 1) {
        m1 = fmaxf(m1, __shfl_xor(m1, o));
        m2 = fmaxf(m2, __shfl_xor(m2, o));
    }
    float e1[16];
    float s1 = 0.f, s2 = 0.f;
#pragma unroll
    for (int i = 0; i < 16; i++) {
        int j = lane + ((i >> 1) << 6);
        if (j < H) {
            e1[i] = __expf(ta[i] - m1);
            s1 += e1[i];
            s2 += __expf(tb[i] - m2);
        } else {
            e1[i] = 0.f;
        }
    }
#pragma unroll
    for (int o = 32; o > 0; o >>= 1) {
        s1 += __shfl_xor(s1, o);
        s2 += __shfl_xor(s2, o);
    }
    float ls1 = __logf(s1), ls2 = __logf(s2);
    float inv = 1.f / s1;
    float kl = 0.f;
#pragma unroll
    for (int i = 0; i < 16; i++) {
        int j = lane + ((i >> 1) << 6);
        if (j < H) {
            float lp = ta[i] - m1 - ls1;
            float lq = tb[i] - m2 - ls2;
            kl += e1[i] * inv * (lp - lq);
        }
    }
#pragma unroll
    for (int o = 32; o > 0; o >>= 1) kl += __shfl_xor(kl, o);
    if (lane == 0) klpart[s] = kl;
}

__global__ void k_final(const float* fpart, const float* klpart, float* out, int nf, int nk) {
    __shared__ float red[256];
    float a = 0.f;
    for (int i = threadIdx.x; i < nf; i += 256) a += fpart[i];
    a = block_sum(a, red);
    float b = 0.f;
    for (int i = threadIdx.x; i < nk; i += 256) b += klpart[i];
    b = block_sum(b, red);
    if (threadIdx.x == 0) {
        out[0] = a;
        out[1] = b;
    }
}

extern "C" void kernel_launch(void* const* d_in, const int* in_sizes, int n_in,
                              void* d_out, int out_size, void* d_ws, size_t ws_size,
                              hipStream_t stream) {
    const float* feature = (const float*)d_in[0];
    const float* logits  = (const float*)d_in[1];
    const int*   targets = (const int*)d_in[2];
    const float* finit   = (const float*)d_in[3];
    const float* linit   = (const float*)d_in[4];

    const int B = in_sizes[2];                 // 16384
    const int D = in_sizes[0] / B;             // 1024
    const int C = in_sizes[3] / D;             // 1000

    float* out = (float*)d_out;
    float* ftab = out + 2;                     // [C, D]
    float* ltab = out + 2 + (long)C * D;       // [C, C]  (S0 scratch + ghist scratch)

    const int G = (B + 255) / 256;             // 64 groups
    const int NT = (C + 63) / 64;              // 16 tiles per dim
    const int NTRI = NT * (NT + 1) / 2;        // 136 triangular tiles

    char* ws = (char*)d_ws;
    int*      counts  = (int*)(ws + 0);        // 1024
    int*      offsets = (int*)(ws + 4096);     // 1024
    int*      idx     = (int*)(ws + 12288);    // 16384
    float*    norms   = (float*)(ws + 77824);  // 1024
    float*    simraw  = (float*)(ws + 81920);  // 1024
    int*      simcls  = (int*)(ws + 86016);    // 1024
    unsigned* minmax  = (unsigned*)(ws + 90112); // 2
    float*    fpart   = (float*)(ws + 90368);  // 4096
    float*    klpart  = (float*)(ws + 106752); // 16384
    float*    S1      = (float*)(ws + 262144); // up to 3 partial buffers follow
    float*    S2      = S1 + (long)C * C;
    float*    S3      = S2 + (long)C * C;

    // pick split-K factor by available ws: 4 -> 2 -> 1
    size_t need4 = 262144 + 3ul * C * C * sizeof(float);
    size_t need2 = 262144 + 1ul * C * C * sizeof(float);
    int split = (ws_size >= need4) ? 4 : (ws_size >= need2) ? 2 : 1;

    // gh scratch lives in the (not-yet-written) ltab output region: G*1024 ints = 256 KB
    int* gh = (int*)ltab;

    k_ghist<<<G, 256, 0, stream>>>(targets, gh, B);
    k_bases<<<1, 1024, 0, stream>>>(gh, counts, offsets, minmax, G, C);
    k_rank_scatter<<<G, 256, 0, stream>>>(targets, offsets, gh, idx, B);

    k_ftab<<<C, 256, 0, stream>>>(feature, finit, counts, offsets, idx, ftab, norms, C, D);

    dim3 ggrid(NTRI, split);
    k_gemm_tri<<<ggrid, 512, 0, stream>>>(ftab, ltab /*S0*/, S1, S2, S3, C, D, D / split, NT);
    k_rowmax<<<C, 256, 0, stream>>>(ltab /*S0*/, S1, S2, S3, split, norms, minmax,
                                    simraw, simcls, C);

    // now overwrite the S0 scratch with the real logit_table
    k_ltab<<<C, 256, 0, stream>>>(logits, linit, counts, offsets, idx, ltab, C, C);

    k_floss<<<B / 4, 256, 0, stream>>>(feature, ftab, norms, targets, minmax, simraw, simcls,
                                       fpart, B, D);
    k_kl<<<B / 4, 256, 0, stream>>>(logits, ltab, targets, klpart, B, C);
    k_final<<<1, 256, 0, stream>>>(fpart, klpart, out, B / 4, B);
}

// Round 13
// 175.555 us; speedup vs baseline: 1.1187x; 1.0906x over previous
//
#include <hip/hip_runtime.h>
#include <hip/hip_bf16.h>
#include <math.h>

#define EPS 1e-8f

// ---------- helpers ----------
__device__ __forceinline__ unsigned fenc(float f) {
    unsigned u = __float_as_uint(f);
    return (u & 0x80000000u) ? ~u : (u | 0x80000000u);
}
__device__ __forceinline__ float fdec(unsigned e) {
    unsigned u = (e & 0x80000000u) ? (e & 0x7FFFFFFFu) : ~e;
    return __uint_as_float(u);
}

__device__ __forceinline__ float block_sum(float v, float* red) {
    red[threadIdx.x] = v;
    __syncthreads();
    for (int k = 128; k > 0; k >>= 1) {
        if (threadIdx.x < k) red[threadIdx.x] += red[threadIdx.x + k];
        __syncthreads();
    }
    float r = red[0];
    __syncthreads();
    return r;
}

// ---------- kernels ----------
// per-group histogram: gh[g*1024 + c]
__global__ void k_ghist(const int* tgt, int* gh, int B) {
    __shared__ int lh[1024];
    int g = blockIdx.x, t = threadIdx.x;
    lh[t] = 0; lh[t + 256] = 0; lh[t + 512] = 0; lh[t + 768] = 0;
    __syncthreads();
    int i = g * 256 + t;
    if (i < B) atomicAdd(&lh[tgt[i]], 1);
    __syncthreads();
    int* dst = gh + g * 1024;
    dst[t] = lh[t]; dst[t + 256] = lh[t + 256];
    dst[t + 512] = lh[t + 512]; dst[t + 768] = lh[t + 768];
}

// in-place exclusive scan of gh over groups (per class), totals -> counts,
// class-exclusive-scan -> offsets. One block, 1024 threads. Also inits minmax.
__global__ void k_bases(int* gh, int* counts, int* offsets, unsigned* minmax, int G, int C) {
    __shared__ int buf[1024];
    int c = threadIdx.x;
    if (c == 0) { minmax[0] = 0xFFFFFFFFu; minmax[1] = 0u; }
    int run = 0;
#pragma unroll 16
    for (int g = 0; g < G; g++) {
        int v = gh[g * 1024 + c];
        gh[g * 1024 + c] = run;
        run += v;
    }
    if (c < C) counts[c] = run;
    int v0 = (c < C) ? run : 0;
    buf[c] = v0;
    __syncthreads();
    for (int off = 1; off < 1024; off <<= 1) {
        int v = (c >= off) ? buf[c - off] : 0;
        __syncthreads();
        buf[c] += v;
        __syncthreads();
    }
    if (c < C) offsets[c] = buf[c] - v0;
}

// stable rank within group via LDS compare-count; deterministic idx
__global__ void k_rank_scatter(const int* tgt, const int* offsets, const int* gh,
                               int* idx, int B) {
    __shared__ int lt[256];
    int g = blockIdx.x, t = threadIdx.x;
    int i = g * 256 + t;
    int my = (i < B) ? tgt[i] : -1;
    lt[t] = my;
    __syncthreads();
    if (i < B) {
        int rank = 0;
        for (int j = 0; j < t; j++) rank += (lt[j] == my);
        idx[offsets[my] + gh[g * 1024 + my] + rank] = i;
    }
}

// one block (256 thr) per class; D = 1024 (256 float4). Also emits norms.
// Software-pipelined gather (prefetch next idx + next row; order preserved).
__global__ void k_ftab(const float* feat, const float* finit, const int* counts,
                       const int* offsets, const int* idx, float* ftab, float* norms,
                       int C, int D) {
    __shared__ float red[256];
    int c = blockIdx.x, t = threadIdx.x;
    int n = counts[c];
    float o0, o1, o2, o3;
    if (n == 0) {
        float4 v = ((const float4*)(finit + (long)c * D))[t];
        o0 = v.x; o1 = v.y; o2 = v.z; o3 = v.w;
    } else {
        float4 acc = {0.f, 0.f, 0.f, 0.f};
        int o = offsets[c];
        int inx = idx[o];
        float4 nxt = ((const float4*)(feat + (long)inx * D))[t];
        for (int i = 0; i < n; i++) {
            float4 cur = nxt;
            if (i + 1 < n) {
                int in2 = idx[o + i + 1];
                nxt = ((const float4*)(feat + (long)in2 * D))[t];
            }
            acc.x += cur.x; acc.y += cur.y; acc.z += cur.z; acc.w += cur.w;
        }
        float inv = 1.0f / (float)n;
        o0 = acc.x * inv; o1 = acc.y * inv; o2 = acc.z * inv; o3 = acc.w * inv;
    }
    float* dst = ftab + (long)c * D + t * 4;   // ftab only 8B-aligned -> scalar writes
    dst[0] = o0; dst[1] = o1; dst[2] = o2; dst[3] = o3;
    float ss = o0 * o0 + o1 * o1 + o2 * o2 + o3 * o3;
    ss = block_sum(ss, red);
    if (t == 0) norms[c] = sqrtf(ss);
}

// one block per class; C2 = 1000 columns (250 float4 per row; logits rows 16B-aligned)
__global__ void k_ltab(const float* logits, const float* linit, const int* counts,
                       const int* offsets, const int* idx, float* ltab, int C, int C2) {
    int c = blockIdx.x, t = threadIdx.x;
    int n = counts[c];
    if (n == 0) {
        for (int d = t; d < C2; d += 256) ltab[(long)c * C2 + d] = linit[(long)c * C2 + d];
        return;
    }
    int nv = C2 >> 2;                 // 250
    if (t < nv) {
        float4 acc = {0.f, 0.f, 0.f, 0.f};
        int o = offsets[c];
        int inx = idx[o];
        float4 nxt = ((const float4*)(logits + (long)inx * C2))[t];
        for (int i = 0; i < n; i++) {
            float4 cur = nxt;
            if (i + 1 < n) {
                int in2 = idx[o + i + 1];
                nxt = ((const float4*)(logits + (long)in2 * C2))[t];
            }
            acc.x += cur.x; acc.y += cur.y; acc.z += cur.z; acc.w += cur.w;
        }
        float inv = 1.0f / (float)n;
        float* dst = ltab + (long)c * C2 + t * 4;  // 8B-aligned -> scalar writes
        dst[0] = acc.x * inv;
        dst[1] = acc.y * inv;
        dst[2] = acc.z * inv;
        dst[3] = acc.w * inv;
    }
}

// Raw-dot triangular GEMM: one block per upper-tri 64x64 tile, 1024 thr (16 waves),
// 8x8 per-thread blocking (spatial 8x8 grid), intra-block split-K=16 (kz = t>>6
// owns 2 k of each 32-k step), double-buffered LDS, tree kz-reduction through 4
// LDS buffers (fixed pairing -> deterministic), cooperative coalesced stores of
// S(r,c) and mirror S(c,r). Plain stores, no atomics.
__global__ __launch_bounds__(1024) void k_gemm_tri(const float* A, float* S,
                                                   int C, int D, int NT) {
    __shared__ __align__(16) float As[2][32][68];
    __shared__ __align__(16) float Bs[2][32][68];
    __shared__ __align__(16) float racc[4][64 * 68];
    int t = threadIdx.x;
    int sp = t & 63;                  // spatial position 0..63
    int tx = sp & 7, ty = sp >> 3;    // 8x8 grid of 8x8-output threads
    int kz = t >> 6;                  // 0..15 (one wave per kz)
    // decode triangular tile index
    int q = blockIdx.x, ti = 0;
    while (q >= NT - ti) { q -= NT - ti; ti++; }
    int tj = ti + q;
    int rb = ti * 64, cb = tj * 64;
    int sr = t >> 4;                  // 0..63 staging row
    int sl = t & 15;                  // 0..15 staging k-lane
    int ga = rb + sr, gb = cb + sr;
    bool okA = ga < C, okB = gb < C;
    const float* arow = A + (long)ga * D;
    const float* brow = A + (long)gb * D;

    float pa[2], pb[2];
#define LOADT(K0)                                                          \
    _Pragma("unroll") for (int j = 0; j < 2; j++) {                        \
        int k = (K0) + sl + 16 * j;                                        \
        pa[j] = okA ? arow[k] : 0.f;                                       \
        pb[j] = okB ? brow[k] : 0.f;                                       \
    }
#define STORET(BUF)                                                        \
    _Pragma("unroll") for (int j = 0; j < 2; j++) {                        \
        int k = sl + 16 * j;                                               \
        As[BUF][k][sr] = pa[j];                                            \
        Bs[BUF][k][sr] = pb[j];                                            \
    }

    LOADT(0)
    STORET(0)
    __syncthreads();
    float acc[8][8] = {};
    int kbase = kz * 2;
    int nsteps = D >> 5;               // 32
    for (int step = 0; step < nsteps; step++) {
        int cur = step & 1;
        if (step < nsteps - 1) {
            LOADT((step + 1) * 32)
        }
#pragma unroll
        for (int kk = 0; kk < 2; kk++) {
            int k = kbase + kk;
            float4 a0 = *reinterpret_cast<const float4*>(&As[cur][k][ty * 8]);
            float4 a1 = *reinterpret_cast<const float4*>(&As[cur][k][ty * 8 + 4]);
            float4 b0 = *reinterpret_cast<const float4*>(&Bs[cur][k][tx * 8]);
            float4 b1 = *reinterpret_cast<const float4*>(&Bs[cur][k][tx * 8 + 4]);
            float a[8] = {a0.x, a0.y, a0.z, a0.w, a1.x, a1.y, a1.z, a1.w};
            float b[8] = {b0.x, b0.y, b0.z, b0.w, b1.x, b1.y, b1.z, b1.w};
#pragma unroll
            for (int i = 0; i < 8; i++)
#pragma unroll
                for (int j = 0; j < 8; j++) acc[i][j] += a[i] * b[j];
        }
        if (step < nsteps - 1) {
            STORET(cur ^ 1)
        }
        __syncthreads();
    }
#undef LOADT
#undef STORET

    // tree reduction over kz (16 -> 1), fixed pairing -> deterministic.
    // WR: dump acc to buffer; RD: acc += buffer. b128, stride-68 rows (bank-uniform).
#define WR(BUF)                                                                      \
    _Pragma("unroll") for (int i = 0; i < 8; i++)                                    \
    _Pragma("unroll") for (int jj = 0; jj < 2; jj++)                                 \
        *reinterpret_cast<float4*>(&racc[BUF][sp * 68 + i * 8 + jj * 4]) =           \
            make_float4(acc[i][jj * 4], acc[i][jj * 4 + 1],                          \
                        acc[i][jj * 4 + 2], acc[i][jj * 4 + 3]);
#define RD(BUF)                                                                      \
    _Pragma("unroll") for (int i = 0; i < 8; i++)                                    \
    _Pragma("unroll") for (int jj = 0; jj < 2; jj++) {                               \
        float4 v4 = *reinterpret_cast<const float4*>(&racc[BUF][sp * 68 + i * 8 + jj * 4]); \
        acc[i][jj * 4] += v4.x; acc[i][jj * 4 + 1] += v4.y;                          \
        acc[i][jj * 4 + 2] += v4.z; acc[i][jj * 4 + 3] += v4.w;                      \
    }

    if (kz >= 8 && kz < 12) { WR(kz - 8) }
    __syncthreads();
    if (kz < 4) { RD(kz) }
    __syncthreads();
    if (kz >= 12) { WR(kz - 12) }
    __syncthreads();
    if (kz >= 4 && kz < 8) { RD(kz - 4) }
    __syncthreads();
    if (kz >= 4 && kz < 8) { WR(kz - 4) }
    __syncthreads();
    if (kz < 4) { RD(kz) }
    __syncthreads();
    if (kz == 2 || kz == 3) { WR(kz - 2) }
    __syncthreads();
    if (kz < 2) { RD(kz) }
    __syncthreads();
    if (kz == 1) { WR(0) }
    __syncthreads();
    if (kz == 0) { RD(0) }
    __syncthreads();
#undef WR
#undef RD

    // stage final 64x64 tile into racc[0] as OutT[row][col] (stride 68)
    if (kz == 0) {
#pragma unroll
        for (int i = 0; i < 8; i++)
#pragma unroll
            for (int jj = 0; jj < 2; jj++)
                *reinterpret_cast<float4*>(&racc[0][(ty * 8 + i) * 68 + tx * 8 + jj * 4]) =
                    make_float4(acc[i][jj * 4], acc[i][jj * 4 + 1],
                                acc[i][jj * 4 + 2], acc[i][jj * 4 + 3]);
    }
    __syncthreads();

    // cooperative stores: all 1024 threads, 4 cols each
    int r0 = t >> 4;                  // 0..63
    int cbl = (t & 15) * 4;           // local col base
    int gr = rb + r0;
    bool edge = (tj == NT - 1);
    if (gr < C) {
        float4 v4 = *reinterpret_cast<const float4*>(&racc[0][r0 * 68 + cbl]);
        float v[4] = {v4.x, v4.y, v4.z, v4.w};
        float* dst = S + (long)gr * C + cb + cbl;
        if (!edge) {
            *reinterpret_cast<float2*>(dst) = make_float2(v[0], v[1]);
            *reinterpret_cast<float2*>(dst + 2) = make_float2(v[2], v[3]);
        } else {
#pragma unroll
            for (int m = 0; m < 4; m++)
                if (cb + cbl + m < C) dst[m] = v[m];
        }
    }
    if (ti != tj) {
        int cc0 = cb + r0;
        if (cc0 < C) {
            float w[4];
#pragma unroll
            for (int m = 0; m < 4; m++) w[m] = racc[0][(cbl + m) * 68 + r0];
            // mirror rows rb+cbl+m: ti<tj implies ti<=NT-2 -> always < C
            float* dst = S + (long)cc0 * C + rb + cbl;
            *reinterpret_cast<float2*>(dst) = make_float2(w[0], w[1]);
            *reinterpret_cast<float2*>(dst + 2) = make_float2(w[2], w[3]);
        }
    }
}

// per-row: best/argmax (excl diag) of cos values + global min/max (incl diag).
// S holds raw dots; divide by norms on the fly (min-max scaling is monotone,
// so argmax/max on raw cos == on scaled; scaling applied later in k_losses).
__global__ void k_rowmax(const float* S, const float* norms, unsigned* minmax,
                         float* simraw, int* simcls, int C) {
    __shared__ float invn[1024];
    __shared__ float rv[256], rmn[256], rmx[256];
    __shared__ int ri[256];
    int c = blockIdx.x, t = threadIdx.x;
    for (int j = t; j < C; j += 256) invn[j] = 1.f / norms[j];
    __syncthreads();
    float inc = invn[c];
    float best = -INFINITY, lmin = INFINITY, lmax = -INFINITY;
    int bi = 0x7FFFFFFF;
    long rowo = (long)c * C;
    for (int j = t; j < C; j += 256) {
        float v = S[rowo + j] * inc * invn[j];
        lmin = fminf(lmin, v);
        lmax = fmaxf(lmax, v);
        if (j != c && v > best) { best = v; bi = j; }
    }
    rv[t] = best; ri[t] = bi; rmn[t] = lmin; rmx[t] = lmax;
    __syncthreads();
    for (int k = 128; k > 0; k >>= 1) {
        if (t < k) {
            if (rv[t + k] > rv[t] || (rv[t + k] == rv[t] && ri[t + k] < ri[t])) {
                rv[t] = rv[t + k];
                ri[t] = ri[t + k];
            }
            rmn[t] = fminf(rmn[t], rmn[t + k]);
            rmx[t] = fmaxf(rmx[t], rmx[t + k]);
        }
        __syncthreads();
    }
    if (t == 0) {
        simraw[c] = rv[0];
        simcls[c] = ri[0];
        atomicMin(&minmax[0], fenc(rmn[0]));
        atomicMax(&minmax[1], fenc(rmx[0]));
    }
}

// Fused losses: blocks [0, FB) do feature loss (wave per sample, 4/block);
// blocks [FB, 2*FB) do KL (wave per sample, 4/block). Independent paths.
__global__ __launch_bounds__(256) void k_losses(
        const float* feat, const float* ftab, const float* norms, const int* tgt,
        const unsigned* minmax, const float* simraw, const int* simcls,
        const float* logits, const float* LT,
        float* fpart, float* klpart, int B, int D, int C, int FB) {
    int wid = threadIdx.x >> 6, lane = threadIdx.x & 63;
    if ((int)blockIdx.x < FB) {
        // ---- feature loss path ----
        int s = blockIdx.x * 4 + wid;
        int cls = tgt[s];
        int sc = simcls[cls];
        const float4* f4 = (const float4*)(feat + (long)s * D);       // 16B-aligned
        const float2* ft2 = (const float2*)(ftab + (long)cls * D);    // 8B-aligned
        const float2* fs2 = (const float2*)(ftab + (long)sc * D);
        float d1 = 0.f, d2 = 0.f, nf2 = 0.f;
#pragma unroll
        for (int i = 0; i < 4; i++) {
            int j = lane + i * 64;       // float4 index, 0..255
            float4 x = f4[j];
            float2 a0 = ft2[2 * j], a1 = ft2[2 * j + 1];
            float2 b0 = fs2[2 * j], b1 = fs2[2 * j + 1];
            d1 += x.x * a0.x + x.y * a0.y + x.z * a1.x + x.w * a1.y;
            d2 += x.x * b0.x + x.y * b0.y + x.z * b1.x + x.w * b1.y;
            nf2 += x.x * x.x + x.y * x.y + x.z * x.z + x.w * x.w;
        }
        for (int o = 32; o > 0; o >>= 1) {
            d1 += __shfl_down(d1, o);
            d2 += __shfl_down(d2, o);
            nf2 += __shfl_down(nf2, o);
        }
        __shared__ float part[4];
        if (lane == 0) {
            float cmin = fdec(minmax[0]);
            float cmax = fdec(minmax[1]);
            float sv = (simraw[cls] - cmin) / (cmax - cmin);
            float nf = fmaxf(sqrtf(nf2), EPS);
            float nt = fmaxf(norms[cls], EPS);
            float ns = fmaxf(norms[sc], EPS);
            part[wid] = (1.f - d1 / (nf * nt)) + (d2 / (nf * ns)) * sv;
        }
        __syncthreads();
        if (threadIdx.x == 0) fpart[blockIdx.x] = part[0] + part[1] + part[2] + part[3];
    } else {
        // ---- KL path ----
        int s = (blockIdx.x - FB) * 4 + wid;
        int cls = tgt[s];
        const float2* a2 = (const float2*)(LT + (long)cls * C);      // 8B-aligned
        const float4* b4 = (const float4*)(logits + (long)s * C);    // 16B-aligned
        int Q = C >> 2;   // 250
        float ta[16], tb[16];
        float m1 = -INFINITY, m2 = -INFINITY;
#pragma unroll
        for (int p = 0; p < 4; p++) {
            int j = lane + (p << 6);
            if (j < Q) {
                float4 vb = b4[j];
                float2 va0 = a2[2 * j], va1 = a2[2 * j + 1];
                ta[4 * p] = va0.x; ta[4 * p + 1] = va0.y;
                ta[4 * p + 2] = va1.x; ta[4 * p + 3] = va1.y;
                tb[4 * p] = vb.x; tb[4 * p + 1] = vb.y;
                tb[4 * p + 2] = vb.z; tb[4 * p + 3] = vb.w;
                m1 = fmaxf(m1, fmaxf(fmaxf(va0.x, va0.y), fmaxf(va1.x, va1.y)));
                m2 = fmaxf(m2, fmaxf(fmaxf(vb.x, vb.y), fmaxf(vb.z, vb.w)));
            } else {
#pragma unroll
                for (int r = 0; r < 4; r++) { ta[4 * p + r] = -INFINITY; tb[4 * p + r] = -INFINITY; }
            }
        }
#pragma unroll
        for (int o = 32; o > 0; o >>= 1) {
            m1 = fmaxf(m1, __shfl_xor(m1, o));
            m2 = fmaxf(m2, __shfl_xor(m2, o));
        }
        float e1[16];
        float s1 = 0.f, s2 = 0.f;
#pragma unroll
        for (int i = 0; i < 16; i++) {
            int j = lane + ((i >> 2) << 6);
            if (j < Q) {
                e1[i] = __expf(ta[i] - m1);
                s1 += e1[i];
                s2 += __expf(tb[i] - m2);
            } else {
                e1[i] = 0.f;
            }
        }
#pragma unroll
        for (int o = 32; o > 0; o >>= 1) {
            s1 += __shfl_xor(s1, o);
            s2 += __shfl_xor(s2, o);
        }
        float ls1 = __logf(s1), ls2 = __logf(s2);
        float inv = 1.f / s1;
        float kl = 0.f;
#pragma unroll
        for (int i = 0; i < 16; i++) {
            int j = lane + ((i >> 2) << 6);
            if (j < Q) {
                float lp = ta[i] - m1 - ls1;
                float lq = tb[i] - m2 - ls2;
                kl += e1[i] * inv * (lp - lq);
            }
        }
#pragma unroll
        for (int o = 32; o > 0; o >>= 1) kl += __shfl_xor(kl, o);
        if (lane == 0) klpart[s] = kl;
    }
}

__global__ void k_final(const float* fpart, const float* klpart, float* out, int nf, int nk) {
    __shared__ float red[256];
    float a = 0.f;
    for (int i = threadIdx.x; i < nf; i += 256) a += fpart[i];
    a = block_sum(a, red);
    float b = 0.f;
    for (int i = threadIdx.x; i < nk; i += 256) b += klpart[i];
    b = block_sum(b, red);
    if (threadIdx.x == 0) {
        out[0] = a;
        out[1] = b;
    }
}

extern "C" void kernel_launch(void* const* d_in, const int* in_sizes, int n_in,
                              void* d_out, int out_size, void* d_ws, size_t ws_size,
                              hipStream_t stream) {
    const float* feature = (const float*)d_in[0];
    const float* logits  = (const float*)d_in[1];
    const int*   targets = (const int*)d_in[2];
    const float* finit   = (const float*)d_in[3];
    const float* linit   = (const float*)d_in[4];

    const int B = in_sizes[2];                 // 16384
    const int D = in_sizes[0] / B;             // 1024
    const int C = in_sizes[3] / D;             // 1000

    float* out = (float*)d_out;
    float* ftab = out + 2;                     // [C, D]
    float* ltab = out + 2 + (long)C * D;       // [C, C]  (S scratch + ghist scratch)

    const int G = (B + 255) / 256;             // 64 groups
    const int NT = (C + 63) / 64;              // 16 tiles per dim
    const int NTRI = NT * (NT + 1) / 2;        // 136 triangular tiles

    char* ws = (char*)d_ws;
    int*      counts  = (int*)(ws + 0);        // 1024
    int*      offsets = (int*)(ws + 4096);     // 1024
    int*      idx     = (int*)(ws + 12288);    // 16384
    float*    norms   = (float*)(ws + 77824);  // 1024
    float*    simraw  = (float*)(ws + 81920);  // 1024
    int*      simcls  = (int*)(ws + 86016);    // 1024
    unsigned* minmax  = (unsigned*)(ws + 90112); // 2
    float*    fpart   = (float*)(ws + 90368);  // 4096
    float*    klpart  = (float*)(ws + 106752); // 16384

    // gh scratch lives in the (not-yet-written) ltab output region: G*1024 ints = 256 KB
    int* gh = (int*)ltab;

    k_ghist<<<G, 256, 0, stream>>>(targets, gh, B);
    k_bases<<<1, 1024, 0, stream>>>(gh, counts, offsets, minmax, G, C);
    k_rank_scatter<<<G, 256, 0, stream>>>(targets, offsets, gh, idx, B);

    k_ftab<<<C, 256, 0, stream>>>(feature, finit, counts, offsets, idx, ftab, norms, C, D);

    k_gemm_tri<<<NTRI, 1024, 0, stream>>>(ftab, ltab /*S scratch*/, C, D, NT);
    k_rowmax<<<C, 256, 0, stream>>>(ltab /*S*/, norms, minmax, simraw, simcls, C);

    // now overwrite the S scratch with the real logit_table
    k_ltab<<<C, 256, 0, stream>>>(logits, linit, counts, offsets, idx, ltab, C, C);

    const int FB = B / 4;
    k_losses<<<2 * FB, 256, 0, stream>>>(feature, ftab, norms, targets, minmax, simraw,
                                         simcls, logits, ltab, fpart, klpart, B, D, C, FB);
    k_final<<<1, 256, 0, stream>>>(fpart, klpart, out, FB, B);
}

// Round 14
// 168.463 us; speedup vs baseline: 1.1658x; 1.0421x over previous
//
#include <hip/hip_runtime.h>
#include <hip/hip_bf16.h>
#include <math.h>

#define EPS 1e-8f

// ---------- helpers ----------
__device__ __forceinline__ unsigned fenc(float f) {
    unsigned u = __float_as_uint(f);
    return (u & 0x80000000u) ? ~u : (u | 0x80000000u);
}
__device__ __forceinline__ float fdec(unsigned e) {
    unsigned u = (e & 0x80000000u) ? (e & 0x7FFFFFFFu) : ~e;
    return __uint_as_float(u);
}

__device__ __forceinline__ float block_sum(float v, float* red) {
    red[threadIdx.x] = v;
    __syncthreads();
    for (int k = 128; k > 0; k >>= 1) {
        if (threadIdx.x < k) red[threadIdx.x] += red[threadIdx.x + k];
        __syncthreads();
    }
    float r = red[0];
    __syncthreads();
    return r;
}

// ---------- kernels ----------
// per-group histogram: gh[g*1024 + c]
__global__ void k_ghist(const int* tgt, int* gh, int B) {
    __shared__ int lh[1024];
    int g = blockIdx.x, t = threadIdx.x;
    lh[t] = 0; lh[t + 256] = 0; lh[t + 512] = 0; lh[t + 768] = 0;
    __syncthreads();
    int i = g * 256 + t;
    if (i < B) atomicAdd(&lh[tgt[i]], 1);
    __syncthreads();
    int* dst = gh + g * 1024;
    dst[t] = lh[t]; dst[t + 256] = lh[t + 256];
    dst[t + 512] = lh[t + 512]; dst[t + 768] = lh[t + 768];
}

// in-place exclusive scan of gh over groups (per class), totals -> counts,
// class-exclusive-scan -> offsets. One block, 1024 threads. Also inits minmax.
__global__ void k_bases(int* gh, int* counts, int* offsets, unsigned* minmax, int G, int C) {
    __shared__ int buf[1024];
    int c = threadIdx.x;
    if (c == 0) { minmax[0] = 0xFFFFFFFFu; minmax[1] = 0u; }
    int run = 0;
#pragma unroll 16
    for (int g = 0; g < G; g++) {
        int v = gh[g * 1024 + c];
        gh[g * 1024 + c] = run;
        run += v;
    }
    if (c < C) counts[c] = run;
    int v0 = (c < C) ? run : 0;
    buf[c] = v0;
    __syncthreads();
    for (int off = 1; off < 1024; off <<= 1) {
        int v = (c >= off) ? buf[c - off] : 0;
        __syncthreads();
        buf[c] += v;
        __syncthreads();
    }
    if (c < C) offsets[c] = buf[c] - v0;
}

// stable rank within group via LDS compare-count; deterministic idx
__global__ void k_rank_scatter(const int* tgt, const int* offsets, const int* gh,
                               int* idx, int B) {
    __shared__ int lt[256];
    int g = blockIdx.x, t = threadIdx.x;
    int i = g * 256 + t;
    int my = (i < B) ? tgt[i] : -1;
    lt[t] = my;
    __syncthreads();
    if (i < B) {
        int rank = 0;
        for (int j = 0; j < t; j++) rank += (lt[j] == my);
        idx[offsets[my] + gh[g * 1024 + my] + rank] = i;
    }
}

// FUSED table build: blocks [0,C) -> feature table + norms; blocks [C,2C) -> logit table.
// Both gather-mean over idx lists, software-pipelined (order preserved).
__global__ void k_tables(const float* feat, const float* finit,
                         const float* logits, const float* linit,
                         const int* counts, const int* offsets, const int* idx,
                         float* ftab, float* ltab, float* norms,
                         int C, int D, int C2) {
    __shared__ float red[256];
    int t = threadIdx.x;
    if ((int)blockIdx.x < C) {
        int c = blockIdx.x;
        int n = counts[c];
        float o0, o1, o2, o3;
        if (n == 0) {
            float4 v = ((const float4*)(finit + (long)c * D))[t];
            o0 = v.x; o1 = v.y; o2 = v.z; o3 = v.w;
        } else {
            float4 acc = {0.f, 0.f, 0.f, 0.f};
            int o = offsets[c];
            int inx = idx[o];
            float4 nxt = ((const float4*)(feat + (long)inx * D))[t];
            for (int i = 0; i < n; i++) {
                float4 cur = nxt;
                if (i + 1 < n) {
                    int in2 = idx[o + i + 1];
                    nxt = ((const float4*)(feat + (long)in2 * D))[t];
                }
                acc.x += cur.x; acc.y += cur.y; acc.z += cur.z; acc.w += cur.w;
            }
            float inv = 1.0f / (float)n;
            o0 = acc.x * inv; o1 = acc.y * inv; o2 = acc.z * inv; o3 = acc.w * inv;
        }
        float* dst = ftab + (long)c * D + t * 4;   // ftab only 8B-aligned -> scalar writes
        dst[0] = o0; dst[1] = o1; dst[2] = o2; dst[3] = o3;
        float ss = o0 * o0 + o1 * o1 + o2 * o2 + o3 * o3;
        ss = block_sum(ss, red);
        if (t == 0) norms[c] = sqrtf(ss);
    } else {
        int c = blockIdx.x - C;
        int n = counts[c];
        if (n == 0) {
            for (int d = t; d < C2; d += 256) ltab[(long)c * C2 + d] = linit[(long)c * C2 + d];
            return;
        }
        int nv = C2 >> 2;                 // 250
        if (t < nv) {
            float4 acc = {0.f, 0.f, 0.f, 0.f};
            int o = offsets[c];
            int inx = idx[o];
            float4 nxt = ((const float4*)(logits + (long)inx * C2))[t];
            for (int i = 0; i < n; i++) {
                float4 cur = nxt;
                if (i + 1 < n) {
                    int in2 = idx[o + i + 1];
                    nxt = ((const float4*)(logits + (long)in2 * C2))[t];
                }
                acc.x += cur.x; acc.y += cur.y; acc.z += cur.z; acc.w += cur.w;
            }
            float inv = 1.0f / (float)n;
            float* dst = ltab + (long)c * C2 + t * 4;  // 8B-aligned -> scalar writes
            dst[0] = acc.x * inv;
            dst[1] = acc.y * inv;
            dst[2] = acc.z * inv;
            dst[3] = acc.w * inv;
        }
    }
}

// standalone versions (fallback path when ws is too small for S)
__global__ void k_ftab(const float* feat, const float* finit, const int* counts,
                       const int* offsets, const int* idx, float* ftab, float* norms,
                       int C, int D) {
    __shared__ float red[256];
    int c = blockIdx.x, t = threadIdx.x;
    int n = counts[c];
    float o0, o1, o2, o3;
    if (n == 0) {
        float4 v = ((const float4*)(finit + (long)c * D))[t];
        o0 = v.x; o1 = v.y; o2 = v.z; o3 = v.w;
    } else {
        float4 acc = {0.f, 0.f, 0.f, 0.f};
        int o = offsets[c];
        int inx = idx[o];
        float4 nxt = ((const float4*)(feat + (long)inx * D))[t];
        for (int i = 0; i < n; i++) {
            float4 cur = nxt;
            if (i + 1 < n) {
                int in2 = idx[o + i + 1];
                nxt = ((const float4*)(feat + (long)in2 * D))[t];
            }
            acc.x += cur.x; acc.y += cur.y; acc.z += cur.z; acc.w += cur.w;
        }
        float inv = 1.0f / (float)n;
        o0 = acc.x * inv; o1 = acc.y * inv; o2 = acc.z * inv; o3 = acc.w * inv;
    }
    float* dst = ftab + (long)c * D + t * 4;
    dst[0] = o0; dst[1] = o1; dst[2] = o2; dst[3] = o3;
    float ss = o0 * o0 + o1 * o1 + o2 * o2 + o3 * o3;
    ss = block_sum(ss, red);
    if (t == 0) norms[c] = sqrtf(ss);
}

__global__ void k_ltab(const float* logits, const float* linit, const int* counts,
                       const int* offsets, const int* idx, float* ltab, int C, int C2) {
    int c = blockIdx.x, t = threadIdx.x;
    int n = counts[c];
    if (n == 0) {
        for (int d = t; d < C2; d += 256) ltab[(long)c * C2 + d] = linit[(long)c * C2 + d];
        return;
    }
    int nv = C2 >> 2;
    if (t < nv) {
        float4 acc = {0.f, 0.f, 0.f, 0.f};
        int o = offsets[c];
        int inx = idx[o];
        float4 nxt = ((const float4*)(logits + (long)inx * C2))[t];
        for (int i = 0; i < n; i++) {
            float4 cur = nxt;
            if (i + 1 < n) {
                int in2 = idx[o + i + 1];
                nxt = ((const float4*)(logits + (long)in2 * C2))[t];
            }
            acc.x += cur.x; acc.y += cur.y; acc.z += cur.z; acc.w += cur.w;
        }
        float inv = 1.0f / (float)n;
        float* dst = ltab + (long)c * C2 + t * 4;
        dst[0] = acc.x * inv;
        dst[1] = acc.y * inv;
        dst[2] = acc.z * inv;
        dst[3] = acc.w * inv;
    }
}

// Raw-dot triangular GEMM: one block per upper-tri 64x64 tile, 1024 thr (16 waves),
// 8x8 per-thread blocking (spatial 8x8 grid), intra-block split-K=16 (kz = t>>6
// owns 2 k of each 32-k step), double-buffered LDS, tree kz-reduction through 4
// LDS buffers (fixed pairing -> deterministic), cooperative coalesced stores of
// S(r,c) and mirror S(c,r). Plain stores, no atomics.
__global__ __launch_bounds__(1024) void k_gemm_tri(const float* A, float* S,
                                                   int C, int D, int NT) {
    __shared__ __align__(16) float As[2][32][68];
    __shared__ __align__(16) float Bs[2][32][68];
    __shared__ __align__(16) float racc[4][64 * 68];
    int t = threadIdx.x;
    int sp = t & 63;                  // spatial position 0..63
    int tx = sp & 7, ty = sp >> 3;    // 8x8 grid of 8x8-output threads
    int kz = t >> 6;                  // 0..15 (one wave per kz)
    // decode triangular tile index
    int q = blockIdx.x, ti = 0;
    while (q >= NT - ti) { q -= NT - ti; ti++; }
    int tj = ti + q;
    int rb = ti * 64, cb = tj * 64;
    int sr = t >> 4;                  // 0..63 staging row
    int sl = t & 15;                  // 0..15 staging k-lane
    int ga = rb + sr, gb = cb + sr;
    bool okA = ga < C, okB = gb < C;
    const float* arow = A + (long)ga * D;
    const float* brow = A + (long)gb * D;

    float pa[2], pb[2];
#define LOADT(K0)                                                          \
    _Pragma("unroll") for (int j = 0; j < 2; j++) {                        \
        int k = (K0) + sl + 16 * j;                                        \
        pa[j] = okA ? arow[k] : 0.f;                                       \
        pb[j] = okB ? brow[k] : 0.f;                                       \
    }
#define STORET(BUF)                                                        \
    _Pragma("unroll") for (int j = 0; j < 2; j++) {                        \
        int k = sl + 16 * j;                                               \
        As[BUF][k][sr] = pa[j];                                            \
        Bs[BUF][k][sr] = pb[j];                                            \
    }

    LOADT(0)
    STORET(0)
    __syncthreads();
    float acc[8][8] = {};
    int kbase = kz * 2;
    int nsteps = D >> 5;               // 32
    for (int step = 0; step < nsteps; step++) {
        int cur = step & 1;
        if (step < nsteps - 1) {
            LOADT((step + 1) * 32)
        }
#pragma unroll
        for (int kk = 0; kk < 2; kk++) {
            int k = kbase + kk;
            float4 a0 = *reinterpret_cast<const float4*>(&As[cur][k][ty * 8]);
            float4 a1 = *reinterpret_cast<const float4*>(&As[cur][k][ty * 8 + 4]);
            float4 b0 = *reinterpret_cast<const float4*>(&Bs[cur][k][tx * 8]);
            float4 b1 = *reinterpret_cast<const float4*>(&Bs[cur][k][tx * 8 + 4]);
            float a[8] = {a0.x, a0.y, a0.z, a0.w, a1.x, a1.y, a1.z, a1.w};
            float b[8] = {b0.x, b0.y, b0.z, b0.w, b1.x, b1.y, b1.z, b1.w};
#pragma unroll
            for (int i = 0; i < 8; i++)
#pragma unroll
                for (int j = 0; j < 8; j++) acc[i][j] += a[i] * b[j];
        }
        if (step < nsteps - 1) {
            STORET(cur ^ 1)
        }
        __syncthreads();
    }
#undef LOADT
#undef STORET

    // tree reduction over kz (16 -> 1), fixed pairing -> deterministic.
#define WR(BUF)                                                                      \
    _Pragma("unroll") for (int i = 0; i < 8; i++)                                    \
    _Pragma("unroll") for (int jj = 0; jj < 2; jj++)                                 \
        *reinterpret_cast<float4*>(&racc[BUF][sp * 68 + i * 8 + jj * 4]) =           \
            make_float4(acc[i][jj * 4], acc[i][jj * 4 + 1],                          \
                        acc[i][jj * 4 + 2], acc[i][jj * 4 + 3]);
#define RD(BUF)                                                                      \
    _Pragma("unroll") for (int i = 0; i < 8; i++)                                    \
    _Pragma("unroll") for (int jj = 0; jj < 2; jj++) {                               \
        float4 v4 = *reinterpret_cast<const float4*>(&racc[BUF][sp * 68 + i * 8 + jj * 4]); \
        acc[i][jj * 4] += v4.x; acc[i][jj * 4 + 1] += v4.y;                          \
        acc[i][jj * 4 + 2] += v4.z; acc[i][jj * 4 + 3] += v4.w;                      \
    }

    if (kz >= 8 && kz < 12) { WR(kz - 8) }
    __syncthreads();
    if (kz < 4) { RD(kz) }
    __syncthreads();
    if (kz >= 12) { WR(kz - 12) }
    __syncthreads();
    if (kz >= 4 && kz < 8) { RD(kz - 4) }
    __syncthreads();
    if (kz >= 4 && kz < 8) { WR(kz - 4) }
    __syncthreads();
    if (kz < 4) { RD(kz) }
    __syncthreads();
    if (kz == 2 || kz == 3) { WR(kz - 2) }
    __syncthreads();
    if (kz < 2) { RD(kz) }
    __syncthreads();
    if (kz == 1) { WR(0) }
    __syncthreads();
    if (kz == 0) { RD(0) }
    __syncthreads();
#undef WR
#undef RD

    // stage final 64x64 tile into racc[0] as OutT[row][col] (stride 68)
    if (kz == 0) {
#pragma unroll
        for (int i = 0; i < 8; i++)
#pragma unroll
            for (int jj = 0; jj < 2; jj++)
                *reinterpret_cast<float4*>(&racc[0][(ty * 8 + i) * 68 + tx * 8 + jj * 4]) =
                    make_float4(acc[i][jj * 4], acc[i][jj * 4 + 1],
                                acc[i][jj * 4 + 2], acc[i][jj * 4 + 3]);
    }
    __syncthreads();

    // cooperative stores: all 1024 threads, 4 cols each
    int r0 = t >> 4;                  // 0..63
    int cbl = (t & 15) * 4;           // local col base
    int gr = rb + r0;
    bool edge = (tj == NT - 1);
    if (gr < C) {
        float4 v4 = *reinterpret_cast<const float4*>(&racc[0][r0 * 68 + cbl]);
        float v[4] = {v4.x, v4.y, v4.z, v4.w};
        float* dst = S + (long)gr * C + cb + cbl;
        if (!edge) {
            *reinterpret_cast<float2*>(dst) = make_float2(v[0], v[1]);
            *reinterpret_cast<float2*>(dst + 2) = make_float2(v[2], v[3]);
        } else {
#pragma unroll
            for (int m = 0; m < 4; m++)
                if (cb + cbl + m < C) dst[m] = v[m];
        }
    }
    if (ti != tj) {
        int cc0 = cb + r0;
        if (cc0 < C) {
            float w[4];
#pragma unroll
            for (int m = 0; m < 4; m++) w[m] = racc[0][(cbl + m) * 68 + r0];
            float* dst = S + (long)cc0 * C + rb + cbl;
            *reinterpret_cast<float2*>(dst) = make_float2(w[0], w[1]);
            *reinterpret_cast<float2*>(dst + 2) = make_float2(w[2], w[3]);
        }
    }
}

// per-row: best/argmax (excl diag) of cos values + global min/max (incl diag).
__global__ void k_rowmax(const float* S, const float* norms, unsigned* minmax,
                         float* simraw, int* simcls, int C) {
    __shared__ float invn[1024];
    __shared__ float rv[256], rmn[256], rmx[256];
    __shared__ int ri[256];
    int c = blockIdx.x, t = threadIdx.x;
    for (int j = t; j < C; j += 256) invn[j] = 1.f / norms[j];
    __syncthreads();
    float inc = invn[c];
    float best = -INFINITY, lmin = INFINITY, lmax = -INFINITY;
    int bi = 0x7FFFFFFF;
    long rowo = (long)c * C;
    for (int j = t; j < C; j += 256) {
        float v = S[rowo + j] * inc * invn[j];
        lmin = fminf(lmin, v);
        lmax = fmaxf(lmax, v);
        if (j != c && v > best) { best = v; bi = j; }
    }
    rv[t] = best; ri[t] = bi; rmn[t] = lmin; rmx[t] = lmax;
    __syncthreads();
    for (int k = 128; k > 0; k >>= 1) {
        if (t < k) {
            if (rv[t + k] > rv[t] || (rv[t + k] == rv[t] && ri[t + k] < ri[t])) {
                rv[t] = rv[t + k];
                ri[t] = ri[t + k];
            }
            rmn[t] = fminf(rmn[t], rmn[t + k]);
            rmx[t] = fmaxf(rmx[t], rmx[t + k]);
        }
        __syncthreads();
    }
    if (t == 0) {
        simraw[c] = rv[0];
        simcls[c] = ri[0];
        atomicMin(&minmax[0], fenc(rmn[0]));
        atomicMax(&minmax[1], fenc(rmx[0]));
    }
}

// Fused losses: blocks [0, FB) do feature loss (wave per sample, 4/block);
// blocks [FB, 2*FB) do KL (wave per sample, 4/block). Independent paths.
__global__ __launch_bounds__(256) void k_losses(
        const float* feat, const float* ftab, const float* norms, const int* tgt,
        const unsigned* minmax, const float* simraw, const int* simcls,
        const float* logits, const float* LT,
        float* fpart, float* klpart, int B, int D, int C, int FB) {
    int wid = threadIdx.x >> 6, lane = threadIdx.x & 63;
    if ((int)blockIdx.x < FB) {
        int s = blockIdx.x * 4 + wid;
        int cls = tgt[s];
        int sc = simcls[cls];
        const float4* f4 = (const float4*)(feat + (long)s * D);
        const float2* ft2 = (const float2*)(ftab + (long)cls * D);
        const float2* fs2 = (const float2*)(ftab + (long)sc * D);
        float d1 = 0.f, d2 = 0.f, nf2 = 0.f;
#pragma unroll
        for (int i = 0; i < 4; i++) {
            int j = lane + i * 64;
            float4 x = f4[j];
            float2 a0 = ft2[2 * j], a1 = ft2[2 * j + 1];
            float2 b0 = fs2[2 * j], b1 = fs2[2 * j + 1];
            d1 += x.x * a0.x + x.y * a0.y + x.z * a1.x + x.w * a1.y;
            d2 += x.x * b0.x + x.y * b0.y + x.z * b1.x + x.w * b1.y;
            nf2 += x.x * x.x + x.y * x.y + x.z * x.z + x.w * x.w;
        }
        for (int o = 32; o > 0; o >>= 1) {
            d1 += __shfl_down(d1, o);
            d2 += __shfl_down(d2, o);
            nf2 += __shfl_down(nf2, o);
        }
        __shared__ float part[4];
        if (lane == 0) {
            float cmin = fdec(minmax[0]);
            float cmax = fdec(minmax[1]);
            float sv = (simraw[cls] - cmin) / (cmax - cmin);
            float nf = fmaxf(sqrtf(nf2), EPS);
            float nt = fmaxf(norms[cls], EPS);
            float ns = fmaxf(norms[sc], EPS);
            part[wid] = (1.f - d1 / (nf * nt)) + (d2 / (nf * ns)) * sv;
        }
        __syncthreads();
        if (threadIdx.x == 0) fpart[blockIdx.x] = part[0] + part[1] + part[2] + part[3];
    } else {
        int s = (blockIdx.x - FB) * 4 + wid;
        int cls = tgt[s];
        const float2* a2 = (const float2*)(LT + (long)cls * C);
        const float4* b4 = (const float4*)(logits + (long)s * C);
        int Q = C >> 2;   // 250
        float ta[16], tb[16];
        float m1 = -INFINITY, m2 = -INFINITY;
#pragma unroll
        for (int p = 0; p < 4; p++) {
            int j = lane + (p << 6);
            if (j < Q) {
                float4 vb = b4[j];
                float2 va0 = a2[2 * j], va1 = a2[2 * j + 1];
                ta[4 * p] = va0.x; ta[4 * p + 1] = va0.y;
                ta[4 * p + 2] = va1.x; ta[4 * p + 3] = va1.y;
                tb[4 * p] = vb.x; tb[4 * p + 1] = vb.y;
                tb[4 * p + 2] = vb.z; tb[4 * p + 3] = vb.w;
                m1 = fmaxf(m1, fmaxf(fmaxf(va0.x, va0.y), fmaxf(va1.x, va1.y)));
                m2 = fmaxf(m2, fmaxf(fmaxf(vb.x, vb.y), fmaxf(vb.z, vb.w)));
            } else {
#pragma unroll
                for (int r = 0; r < 4; r++) { ta[4 * p + r] = -INFINITY; tb[4 * p + r] = -INFINITY; }
            }
        }
#pragma unroll
        for (int o = 32; o > 0; o >>= 1) {
            m1 = fmaxf(m1, __shfl_xor(m1, o));
            m2 = fmaxf(m2, __shfl_xor(m2, o));
        }
        float e1[16];
        float s1 = 0.f, s2 = 0.f;
#pragma unroll
        for (int i = 0; i < 16; i++) {
            int j = lane + ((i >> 2) << 6);
            if (j < Q) {
                e1[i] = __expf(ta[i] - m1);
                s1 += e1[i];
                s2 += __expf(tb[i] - m2);
            } else {
                e1[i] = 0.f;
            }
        }
#pragma unroll
        for (int o = 32; o > 0; o >>= 1) {
            s1 += __shfl_xor(s1, o);
            s2 += __shfl_xor(s2, o);
        }
        float ls1 = __logf(s1), ls2 = __logf(s2);
        float inv = 1.f / s1;
        float kl = 0.f;
#pragma unroll
        for (int i = 0; i < 16; i++) {
            int j = lane + ((i >> 2) << 6);
            if (j < Q) {
                float lp = ta[i] - m1 - ls1;
                float lq = tb[i] - m2 - ls2;
                kl += e1[i] * inv * (lp - lq);
            }
        }
#pragma unroll
        for (int o = 32; o > 0; o >>= 1) kl += __shfl_xor(kl, o);
        if (lane == 0) klpart[s] = kl;
    }
}

__global__ void k_final(const float* fpart, const float* klpart, float* out, int nf, int nk) {
    __shared__ float red[256];
    float a = 0.f;
    for (int i = threadIdx.x; i < nf; i += 256) a += fpart[i];
    a = block_sum(a, red);
    float b = 0.f;
    for (int i = threadIdx.x; i < nk; i += 256) b += klpart[i];
    b = block_sum(b, red);
    if (threadIdx.x == 0) {
        out[0] = a;
        out[1] = b;
    }
}

extern "C" void kernel_launch(void* const* d_in, const int* in_sizes, int n_in,
                              void* d_out, int out_size, void* d_ws, size_t ws_size,
                              hipStream_t stream) {
    const float* feature = (const float*)d_in[0];
    const float* logits  = (const float*)d_in[1];
    const int*   targets = (const int*)d_in[2];
    const float* finit   = (const float*)d_in[3];
    const float* linit   = (const float*)d_in[4];

    const int B = in_sizes[2];                 // 16384
    const int D = in_sizes[0] / B;             // 1024
    const int C = in_sizes[3] / D;             // 1000

    float* out = (float*)d_out;
    float* ftab = out + 2;                     // [C, D]
    float* ltab = out + 2 + (long)C * D;       // [C, C]

    const int G = (B + 255) / 256;             // 64 groups
    const int NT = (C + 63) / 64;              // 16 tiles per dim
    const int NTRI = NT * (NT + 1) / 2;        // 136 triangular tiles

    char* ws = (char*)d_ws;
    int*      counts  = (int*)(ws + 0);        // 1024
    int*      offsets = (int*)(ws + 4096);     // 1024
    int*      idx     = (int*)(ws + 12288);    // 16384
    float*    norms   = (float*)(ws + 77824);  // 1024
    float*    simraw  = (float*)(ws + 81920);  // 1024
    int*      simcls  = (int*)(ws + 86016);    // 1024
    unsigned* minmax  = (unsigned*)(ws + 90112); // 2
    float*    fpart   = (float*)(ws + 90368);  // 4096
    float*    klpart  = (float*)(ws + 106752); // 16384
    float*    Sws     = (float*)(ws + 262144); // C*C floats (S scratch), if room

    // S in ws (proven ws_size >= 12.25 MB by round-12's split-4 run); fallback kept.
    int sInWs = (ws_size >= 262144 + (size_t)C * C * sizeof(float)) ? 1 : 0;

    // gh scratch lives in the (not-yet-written) ltab output region: G*1024 ints = 256 KB
    int* gh = (int*)ltab;

    k_ghist<<<G, 256, 0, stream>>>(targets, gh, B);
    k_bases<<<1, 1024, 0, stream>>>(gh, counts, offsets, minmax, G, C);
    k_rank_scatter<<<G, 256, 0, stream>>>(targets, offsets, gh, idx, B);

    if (sInWs) {
        // fused table build fills the machine (2000 blocks, both input streams)
        k_tables<<<2 * C, 256, 0, stream>>>(feature, finit, logits, linit,
                                            counts, offsets, idx, ftab, ltab, norms, C, D, C);
        k_gemm_tri<<<NTRI, 1024, 0, stream>>>(ftab, Sws, C, D, NT);
        k_rowmax<<<C, 256, 0, stream>>>(Sws, norms, minmax, simraw, simcls, C);
    } else {
        k_ftab<<<C, 256, 0, stream>>>(feature, finit, counts, offsets, idx, ftab, norms, C, D);
        k_gemm_tri<<<NTRI, 1024, 0, stream>>>(ftab, ltab /*S scratch*/, C, D, NT);
        k_rowmax<<<C, 256, 0, stream>>>(ltab, norms, minmax, simraw, simcls, C);
        k_ltab<<<C, 256, 0, stream>>>(logits, linit, counts, offsets, idx, ltab, C, C);
    }

    const int FB = B / 4;
    k_losses<<<2 * FB, 256, 0, stream>>>(feature, ftab, norms, targets, minmax, simraw,
                                         simcls, logits, ltab, fpart, klpart, B, D, C, FB);
    k_final<<<1, 256, 0, stream>>>(fpart, klpart, out, FB, B);
}